// Round 15
// baseline (154.186 us; speedup 1.0000x reference)
//
#include <hip/hip_runtime.h>
#include <hip/hip_bf16.h>
#include <math.h>

#define B_TOT 8192
#define OBS   4096
#define NG    4
#define GSZ   1024
#define LATD  64
#define HDIM  128

typedef __attribute__((ext_vector_type(8))) short   short8_t;
typedef __attribute__((ext_vector_type(8))) unsigned short ushort8_t;
typedef __attribute__((ext_vector_type(4))) float   float4_t;

__constant__ int kMask[15] = {1,2,4,8, 3,5,9,6,10,12, 7,11,13,14, 15};

static __device__ __forceinline__ unsigned short f2b(float x) {
  __hip_bfloat16 b = __float2bfloat16(x);
  return *reinterpret_cast<unsigned short*>(&b);
}
static __device__ __forceinline__ unsigned int pack2(float lo, float hi) {
  return (unsigned int)f2b(lo) | ((unsigned int)f2b(hi) << 16);
}
// async global->LDS, 16B/lane; dest = wave-uniform base (+lane*16), src per-lane
static __device__ __forceinline__ void gl16(const void* g, void* l) {
  __builtin_amdgcn_global_load_lds(
      (const __attribute__((address_space(1))) void*)g,
      (__attribute__((address_space(3))) void*)l, 16, 0, 0);
}

// slot-padded A rows: 4 rows x 256B per 1056B slot
#define SLOT 1056
#define AQ(row) ((((row) >> 2) * SLOT) + (((row) & 3) * 256))

// ------- fused prep: weight panels + X de-interleave (verified R14) --------
#define N1 524288
#define N2 65536
#define N3 16384
#define N4 262144
__global__ __launch_bounds__(512) void k_prep0(const float* __restrict__ w1,
                                               const float* __restrict__ w2,
                                               const float* __restrict__ w3,
                                               const float* __restrict__ w4,
                                               const float* __restrict__ X,
                                               unsigned short* __restrict__ W1p,
                                               unsigned short* __restrict__ W2p,
                                               unsigned short* __restrict__ W3p,
                                               unsigned short* __restrict__ W4p,
                                               unsigned short* __restrict__ Xt) {
  const int bx = blockIdx.x;
  if (bx >= 1696) {
    const int t = threadIdx.x;
    const int b = (bx - 1696) * 2 + (t >> 8);
    const int t256 = t & 255;
    const float* p = X + (size_t)b * OBS + t256 * 16;
    const float4_t f0 = *(const float4_t*)(p);
    const float4_t f1 = *(const float4_t*)(p + 4);
    const float4_t f2 = *(const float4_t*)(p + 8);
    const float4_t f3 = *(const float4_t*)(p + 12);
    const int k0 = t256 * 4;
    unsigned short* q = Xt + (size_t)b * OBS;
#pragma unroll
    for (int g = 0; g < 4; ++g) {
      uint2 v;
      v.x = pack2(f0[g], f1[g]);
      v.y = pack2(f2[g], f3[g]);
      *(uint2*)(q + g * GSZ + k0) = v;
    }
    return;
  }
  const int i = bx * 512 + threadIdx.x;
  if (i < N1) {
    const int j = i & 7, oct = (i >> 3) & 3, l15 = (i >> 5) & 15;
    const int ni = (i >> 9) & 1, ks = (i >> 10) & 31;
    const int w = (i >> 15) & 3, g = (i >> 17) & 3;
    const int k = ks * 32 + oct * 8 + j;
    const int h = w * 32 + ni * 16 + l15;
    W1p[i] = f2b(w1[g * 131072 + k * 128 + h]);
  } else if (i < N1 + N2) {
    const int idx = i - N1;
    const int j = idx & 7, oct = (idx >> 3) & 3, l15 = (idx >> 5) & 15;
    const int ni = (idx >> 9) & 7, ks = (idx >> 12) & 3, g = (idx >> 14) & 3;
    const int k = ks * 32 + oct * 8 + j;
    const int col = ni * 16 + l15;
    W2p[idx] = f2b(w2[g * 16384 + k * 128 + col]);
  } else if (i < N1 + N2 + N3) {
    const int idx = i - N1 - N2;
    const int j = idx & 7, oct = (idx >> 3) & 3, l15 = (idx >> 5) & 15;
    const int ni = (idx >> 9) & 3, ks = (idx >> 11) & 1, g = (idx >> 12) & 3;
    const int k = ks * 32 + oct * 8 + j;
    const int m = ni * 16 + l15;
    W3p[idx] = f2b(w3[g * 4096 + k * 64 + m]);
  } else {
    const int idx = i - N1 - N2 - N3;
    const int j = idx & 7, oct = (idx >> 3) & 3, l15 = (idx >> 5) & 15;
    const int ni = (idx >> 9) & 1, ks = (idx >> 10) & 1;
    const int oh = (idx >> 11) & 1, ob = (idx >> 12) & 15, g = (idx >> 16) & 3;
    const int k = ks * 32 + oct * 8 + j;
    const int o = ob * 64 + oh * 32 + ni * 16 + l15;
    W4p[idx] = f2b(w4[g * 65536 + k * 1024 + o]);
  }
}

// -------- enc1e: 64-row x 128-col (full-group) blocks, K=1024 --------------
// grid (128 rb, 4 g) = 512 blocks x 512 thr (8 waves: wm=w&3 16-row grp,
// wn=w>>2 64-col half). A read ONCE (Xt 64MB); B panels L2 (128MB). Same
// verified gl16/slot/dbuf staging; 8 chunks BK=128; coalesced Hrow out.
__global__ __launch_bounds__(512, 4) void k_enc1e(const unsigned short* __restrict__ Xt,
                                                  const unsigned short* __restrict__ W1p,
                                                  const float* __restrict__ B1,
                                                  unsigned short* __restrict__ Hrow) {
  __shared__ __align__(16) char As[2 * 16 * SLOT];   // 33.8 KB

  const int tid = threadIdx.x;
  const int w   = tid >> 6;
  const int l   = tid & 63;
  const int wm  = w & 3;            // 16-row group
  const int wn  = w >> 2;           // 64-col half
  const int l15 = l & 15;
  const int oct = l >> 4;
  const int rb  = blockIdx.x * 64;
  const int g   = blockIdx.y;
  const int lofs = (l15 * 4 + oct) * 8;

  const unsigned short* const xsrc =
      Xt + (size_t)(rb + (l >> 4)) * OBS + g * GSZ + (l & 15) * 8;

  // prologue: stage chunk 0 into buf 0 (8 waves x 2 slots = 16 slots)
#pragma unroll
  for (int i = 0; i < 2; ++i) {
    const int s = i * 8 + w;        // slot 0..15 (4 rows each)
    gl16(xsrc + (size_t)(s * 4) * OBS, As + s * SLOT);
  }
  __syncthreads();

  float4_t acc[4];
#pragma unroll
  for (int j = 0; j < 4; ++j) acc[j] = (float4_t){0.f, 0.f, 0.f, 0.f};

  const unsigned short* const bbase = W1p + (size_t)(g * 4) * 32768 + lofs;

  for (int c = 0; c < 8; ++c) {
    const int cur = c & 1;
    if (c < 7) {   // async-prefetch next chunk into alt buffer
#pragma unroll
      for (int i = 0; i < 2; ++i) {
        const int s = i * 8 + w;
        gl16(xsrc + (size_t)(s * 4) * OBS + (c + 1) * 128,
             As + (cur ^ 1) * 16 * SLOT + s * SLOT);
      }
    }
#pragma unroll
    for (int ks = 0; ks < 4; ++ks) {
      const int ksg = c * 4 + ks;
      const short8_t af = *(const short8_t*)(As + cur * 16 * SLOT +
                                             AQ(wm * 16 + l15) +
                                             ks * 64 + oct * 16);
      short8_t bf[4];
#pragma unroll
      for (int ni = 0; ni < 4; ++ni)
        bf[ni] = *(const short8_t*)(bbase + (size_t)(wn * 2 + (ni >> 1)) * 32768 +
                                    (size_t)ksg * 1024 + (ni & 1) * 512);
#pragma unroll
      for (int ni = 0; ni < 4; ++ni)
        acc[ni] = __builtin_amdgcn_mfma_f32_16x16x32_bf16(af, bf[ni], acc[ni], 0, 0, 0);
    }
    __syncthreads();
  }

  // epilogue: h = relu(acc+b1) -> ob (overlays As) -> coalesced Hrow
  unsigned short* const ob = (unsigned short*)As;   // [64][136]
#pragma unroll
  for (int ni = 0; ni < 4; ++ni) {
    const int c128 = wn * 64 + ni * 16 + l15;        // 0..127
    const float b  = B1[g * 128 + c128];
#pragma unroll
    for (int j = 0; j < 4; ++j)
      ob[(wm * 16 + oct * 4 + j) * 136 + c128] = f2b(fmaxf(acc[ni][j] + b, 0.0f));
  }
  __syncthreads();
  {
    const int row = tid >> 3, seg = tid & 7;         // 64 rows x 8 segs of 16
    unsigned short* dst = Hrow + (size_t)(rb + row) * 512 + g * 128 + seg * 16;
    const unsigned short* src = &ob[row * 136 + seg * 16];
    *(ushort8_t*)(dst)     = *(const ushort8_t*)(src);
    *(ushort8_t*)(dst + 8) = *(const ushort8_t*)(src + 8);
  }
}

// -------- enc2d: dec2-clone GEMM: Mlg = Hrow @ W2 + b2 (fp32) --------------
// grid (256 rb, 4 g) = 1024 blocks x 256 thr (4 waves; wave = 32-col qtr).
// Barrier-free K=128 loop; A direct from Hrow (16B/lane), B = W2p panels.
__global__ __launch_bounds__(256) void k_enc2d(const unsigned short* __restrict__ Hrow,
                                               const unsigned short* __restrict__ W2p,
                                               const float* __restrict__ B2,
                                               float* __restrict__ Mlg) {
  __shared__ __align__(16) float obuf[32 * 132];     // 16.9 KB

  const int tid = threadIdx.x;
  const int cq  = tid >> 6;        // col quarter 0..3
  const int l   = tid & 63;
  const int l15 = l & 15;
  const int oct = l >> 4;
  const int rb  = blockIdx.x * 32;
  const int g   = blockIdx.y;
  const int lofs = (l15 * 4 + oct) * 8;

  float4_t acc[2][2];
#pragma unroll
  for (int i = 0; i < 2; ++i)
#pragma unroll
    for (int j = 0; j < 2; ++j) acc[i][j] = (float4_t){0.f, 0.f, 0.f, 0.f};

  const unsigned short* const bb = W2p + (size_t)g * 16384 + lofs;

#pragma unroll
  for (int ks = 0; ks < 4; ++ks) {
    short8_t af[2], bf[2];
#pragma unroll
    for (int mi = 0; mi < 2; ++mi)
      af[mi] = *(const short8_t*)(Hrow + (size_t)(rb + mi * 16 + l15) * 512 +
                                  g * 128 + ks * 32 + oct * 8);
#pragma unroll
    for (int ni = 0; ni < 2; ++ni)
      bf[ni] = *(const short8_t*)(bb + ks * 4096 + (cq * 2 + ni) * 512);
#pragma unroll
    for (int mi = 0; mi < 2; ++mi)
#pragma unroll
      for (int ni = 0; ni < 2; ++ni)
        acc[mi][ni] = __builtin_amdgcn_mfma_f32_16x16x32_bf16(af[mi], bf[ni], acc[mi][ni], 0, 0, 0);
  }

#pragma unroll
  for (int ni = 0; ni < 2; ++ni) {
    const int c128 = cq * 32 + ni * 16 + l15;
    const float b = B2[g * 128 + c128];
#pragma unroll
    for (int mi = 0; mi < 2; ++mi)
#pragma unroll
      for (int j = 0; j < 4; ++j)
        obuf[(mi * 16 + oct * 4 + j) * 132 + c128] = acc[mi][ni][j] + b;
  }
  __syncthreads();

  {
    const int row = tid >> 3, seg = tid & 7;          // 32 rows x 8 segs of 16
    float* dst = Mlg + (size_t)(rb + row) * 512 + g * 128 + seg * 16;
    const float* src = &obuf[row * 132 + seg * 16];
#pragma unroll
    for (int i = 0; i < 4; ++i)
      *(float4*)(dst + i * 4) = *(const float4*)(src + i * 4);
  }
}

// -------- k_poe: PoE + reparameterize + dec1 -> Hd (verified R10 k_samp) ---
__global__ __launch_bounds__(256, 2) void k_poe(const float* __restrict__ Mlg,
                                                const unsigned short* __restrict__ W3p,
                                                const float* __restrict__ DB1,
                                                const float* __restrict__ eps,
                                                const int*   __restrict__ subset_idx,
                                                unsigned short* __restrict__ Hd) {
  __shared__ __align__(16) float mls16[16 * 516];
  __shared__ __align__(16) unsigned short zbs[16 * 72];
  __shared__ __align__(16) char lW3[32768];

  const int tid = threadIdx.x;
  const int w   = tid >> 6;
  const int l   = tid & 63;
  const int l15 = l & 15;
  const int oct = l >> 4;
  const int rb  = blockIdx.x * 16;
  const int lofs = (l15 * 4 + oct) * 16;

#pragma unroll
  for (int i = 0; i < 8; ++i)
    gl16((const char*)W3p + (w * 8 + i) * 1024 + l * 16, lW3 + (w * 8 + i) * 1024);
  {
    const int row = tid >> 4, c0 = (tid & 15) * 32;
    const float* src = Mlg + (size_t)(rb + row) * 512 + c0;
#pragma unroll
    for (int i = 0; i < 8; ++i)
      *(float4*)&mls16[row * 516 + c0 + i * 4] = *(const float4*)(src + i * 4);
  }
  __syncthreads();

#pragma unroll
  for (int qq = 0; qq < 4; ++qq) {
    const int idx = qq * 256 + tid;
    const int r   = idx >> 6;
    const int ll  = idx & 63;
    const int m   = kMask[subset_idx[rb + r]];
    float tau = 1.0f, num = 0.0f;
#pragma unroll
    for (int gg = 0; gg < 4; ++gg) {
      if (m & (1 << gg)) {
        const float lv = mls16[r * 516 + gg * 128 + 64 + ll];
        const float mu = mls16[r * 516 + gg * 128 + ll];
        const float t  = expf(-lv);
        tau += t;
        num = fmaf(t, mu, num);
      }
    }
    const float zv = num / tau + eps[(size_t)(rb + r) * LATD + ll] * rsqrtf(tau);
    zbs[r * 72 + ll] = f2b(zv);
  }
  __syncthreads();

  float4_t a3[4];
#pragma unroll
  for (int j = 0; j < 4; ++j) a3[j] = (float4_t){0.f, 0.f, 0.f, 0.f};
#pragma unroll
  for (int ks = 0; ks < 2; ++ks) {
    const short8_t af = *(const short8_t*)((const char*)zbs +
                        (l15 * 72 + ks * 32 + oct * 8) * 2);
#pragma unroll
    for (int ni = 0; ni < 4; ++ni) {
      const short8_t bf = *(const short8_t*)(lW3 + w * 8192 + ks * 4096 +
                                             ni * 1024 + lofs);
      a3[ni] = __builtin_amdgcn_mfma_f32_16x16x32_bf16(af, bf, a3[ni], 0, 0, 0);
    }
  }
#pragma unroll
  for (int ni = 0; ni < 4; ++ni) {
    const int col = w * 64 + ni * 16 + l15;
    const float b = DB1[col];
#pragma unroll
    for (int j = 0; j < 4; ++j)
      Hd[(size_t)(rb + oct * 4 + j) * 256 + col] = f2b(fmaxf(a3[ni][j] + b, 0.0f));
  }
}

// ---------------- dec2: panel-B MFMA + coalesced epilogue (verified) -------
__global__ __launch_bounds__(512) void k_dec2(const unsigned short* __restrict__ Hd,
                                              const unsigned short* __restrict__ W4p,
                                              const float* __restrict__ Bb,
                                              float* __restrict__ Out) {
  __shared__ float obuf[32][264];

  const int tid = threadIdx.x;
  const int w   = tid >> 6;
  const int l   = tid & 63;
  const int g   = w >> 1;
  const int oh  = w & 1;
  const int r0  = blockIdx.x * 32;
  const int ob  = blockIdx.y * 64;
  const int l15 = l & 15;
  const int oct = l >> 4;
  const int lofs = (l15 * 4 + oct) * 8;

  float4_t acc[2][2];
#pragma unroll
  for (int i = 0; i < 2; ++i)
#pragma unroll
    for (int j = 0; j < 2; ++j) acc[i][j] = (float4_t){0.f, 0.f, 0.f, 0.f};

  const unsigned short* bb4 = W4p + ((g * 16 + blockIdx.y) * 2 + oh) * 2048 + lofs;

#pragma unroll
  for (int ks = 0; ks < 2; ++ks) {
    short8_t af[2], bf[2];
#pragma unroll
    for (int mi = 0; mi < 2; ++mi)
      af[mi] = *(const short8_t*)(Hd + (size_t)(r0 + mi * 16 + l15) * 256 +
                                  g * 64 + ks * 32 + oct * 8);
#pragma unroll
    for (int ni = 0; ni < 2; ++ni)
      bf[ni] = *(const short8_t*)(bb4 + ks * 1024 + ni * 512);
#pragma unroll
    for (int mi = 0; mi < 2; ++mi)
#pragma unroll
      for (int ni = 0; ni < 2; ++ni)
        acc[mi][ni] = __builtin_amdgcn_mfma_f32_16x16x32_bf16(af[mi], bf[ni], acc[mi][ni], 0, 0, 0);
  }

#pragma unroll
  for (int ni = 0; ni < 2; ++ni) {
    const int lo = oh * 32 + ni * 16 + l15;
    const float b = Bb[g * 1024 + ob + lo];
#pragma unroll
    for (int mi = 0; mi < 2; ++mi) {
      const int rloc = mi * 16 + oct * 4;
#pragma unroll
      for (int j = 0; j < 4; ++j)
        obuf[rloc + j][4 * lo + g] = acc[mi][ni][j] + b;
    }
  }
  __syncthreads();

#pragma unroll
  for (int i = 0; i < 4; ++i) {
    const int q = tid + i * 512;
    const int row = q >> 6, c4 = q & 63;
    const float4 v = *(const float4*)&obuf[row][c4 * 4];
    *(float4*)(Out + (size_t)(r0 + row) * OBS + 4 * ob + c4 * 4) = v;
  }
}

extern "C" void kernel_launch(void* const* d_in, const int* in_sizes, int n_in,
                              void* d_out, int out_size, void* d_ws, size_t ws_size,
                              hipStream_t stream) {
  const float* X          = (const float*)d_in[0];
  const float* eps        = (const float*)d_in[1];
  const int*   subset_idx = (const int*)  d_in[2];
  const float* enc_w1     = (const float*)d_in[3];
  const float* enc_b1     = (const float*)d_in[4];
  const float* enc_w2     = (const float*)d_in[5];
  const float* enc_b2     = (const float*)d_in[6];
  const float* dec_w1     = (const float*)d_in[7];
  const float* dec_b1     = (const float*)d_in[8];
  const float* dec_w2     = (const float*)d_in[9];
  const float* dec_b2     = (const float*)d_in[10];
  float* out = (float*)d_out;

  char* wsb = (char*)d_ws;
  unsigned short* Xt   = (unsigned short*)wsb;                                // 64 MB
  unsigned short* Hrow = (unsigned short*)(wsb + (64u << 20));                // 8 MB
  float*          Mlg  = (float*)(wsb + (72u << 20));                         // 16 MB
  unsigned short* Hd   = (unsigned short*)(wsb + (88u << 20));                // 4 MB
  unsigned short* W1p  = (unsigned short*)(wsb + (92u << 20));                // 1 MB
  unsigned short* W2p  = (unsigned short*)(wsb + (93u << 20));                // 128 KB
  unsigned short* W3p  = (unsigned short*)(wsb + (93u << 20) + (128u << 10)); // 32 KB
  unsigned short* W4p  = (unsigned short*)(wsb + (93u << 20) + (160u << 10)); // 512 KB

  k_prep0<<<5792, 512, 0, stream>>>(enc_w1, enc_w2, dec_w1, dec_w2, X,
                                    W1p, W2p, W3p, W4p, Xt);
  k_enc1e<<<dim3(128, 4), 512, 0, stream>>>(Xt, W1p, enc_b1, Hrow);
  k_enc2d<<<dim3(256, 4), 256, 0, stream>>>(Hrow, W2p, enc_b2, Mlg);
  k_poe<<<512, 256, 0, stream>>>(Mlg, W3p, dec_b1, eps, subset_idx, Hd);
  k_dec2<<<dim3(256, 16), 512, 0, stream>>>(Hd, W4p, dec_b2, out);
}